// Round 1
// baseline (746.259 us; speedup 1.0000x reference)
//
#include <hip/hip_runtime.h>

typedef __attribute__((ext_vector_type(4))) float f32x4;
typedef __attribute__((ext_vector_type(8))) short s16x8;
typedef unsigned short u16;

#define KGEN 32
#define NTAPS 28

__device__ __forceinline__ float bf2f(u16 v) {
    return __uint_as_float(((unsigned)v) << 16);
}
__device__ __forceinline__ u16 f2bf(float f) {
    unsigned u = __float_as_uint(f);
    unsigned r = (u + 0x7fffu + ((u >> 16) & 1u)) >> 16;
    return (u16)r;
}

// async 16B global -> LDS (wave-uniform LDS base + lane*16 pattern)
#define ASYNC_COPY16(gptr, lptr)                                               \
    __builtin_amdgcn_global_load_lds(                                          \
        (const __attribute__((address_space(1))) unsigned int*)(gptr),         \
        (__attribute__((address_space(3))) unsigned int*)(lptr), 16, 0, 0)

// ---------------------------------------------------------------------------
// K1: generate hz/vt depthwise taps.  2 blocks (0=hz,1=vt) x 256 threads.
// hzvt layout: [2][256][3] fp32
// ---------------------------------------------------------------------------
__global__ __launch_bounds__(256) void gen_kernel(
    const float* __restrict__ freqs, const float* __restrict__ phases,
    const float* __restrict__ hz_outdim, const float* __restrict__ vt_outdim,
    const float* __restrict__ gsig, const float* __restrict__ low_filter,
    const float* __restrict__ gauss_x, float* __restrict__ hzvt)
{
    const int which = blockIdx.x;   // 0 = hz (freqs[:,0]), 1 = vt (freqs[:,1])
    const int i = threadIdx.x;      // row 0..255

    __shared__ float basis[256][KGEN];   // 32 KB; later reused as wtab
    __shared__ float red[256];
    __shared__ float colscale[KGEN];

    {
        float f = freqs[i * 2 + which];
        float p = phases[i];
        #pragma unroll
        for (int j = 0; j < KGEN; j++) {
            float g = ((float)j - 15.5f) * (2.0f / 33.0f);
            basis[i][j] = sinf((f * g + p) * 6.283185307179586f) * 0.6065306597126334f;
        }
    }
    __syncthreads();

    const float* coeff = (which == 0) ? hz_outdim : vt_outdim;
    float acc[KGEN];
    #pragma unroll
    for (int j = 0; j < KGEN; j++) acc[j] = 0.f;

    const float4* crow = (const float4*)(coeff + (size_t)i * 256);
    for (int c4 = 0; c4 < 64; c4++) {
        float4 cv = crow[c4];
        int c = c4 * 4;
        #pragma unroll
        for (int j = 0; j < KGEN; j++) {
            acc[j] += basis[c][j] * cv.x + basis[c + 1][j] * cv.y
                    + basis[c + 2][j] * cv.z + basis[c + 3][j] * cv.w;
        }
    }
    #pragma unroll
    for (int j = 0; j < KGEN; j++) acc[j] *= 0.0625f;  // 1/sqrt(256)

    // global mean over all 256*32 entries
    float s = 0.f;
    #pragma unroll
    for (int j = 0; j < KGEN; j++) s += acc[j];
    red[i] = s;
    __syncthreads();
    for (int st = 128; st > 0; st >>= 1) {
        if (i < st) red[i] += red[i + st];
        __syncthreads();
    }
    float mean = red[0] * (1.0f / 8192.0f);
    #pragma unroll
    for (int j = 0; j < KGEN; j++) acc[j] -= mean;

    // per-column RMS normalize (mean over rows of w^2)
    #pragma unroll
    for (int j = 0; j < KGEN; j++) basis[i][j] = acc[j];  // reuse as wtab
    __syncthreads();
    if (i < KGEN) {
        float ss = 0.f;
        for (int r = 0; r < 256; r++) { float v = basis[r][i]; ss += v * v; }
        colscale[i] = rsqrtf(ss * (1.0f / 256.0f) + 1e-8f);
    }
    __syncthreads();

    float sg = gsig[0];
    float gs = 1.0f + sg * sg * 0.2f;
    #pragma unroll
    for (int j = 0; j < KGEN; j++) {
        float gx = gauss_x[j];
        acc[j] = acc[j] * colscale[j] * expf(-(gx * gx) / (2.0f * gs));
    }

    // valid correlation with 28-tap low-pass, take outputs 0,2,4
    float lf[NTAPS];
    #pragma unroll
    for (int t = 0; t < NTAPS; t++) lf[t] = low_filter[t];
    #pragma unroll
    for (int p = 0; p < 3; p++) {
        int t0 = 2 * p;
        float o = 0.f;
        #pragma unroll
        for (int t = 0; t < NTAPS; t++) o += acc[t0 + t] * lf[t];
        hzvt[((size_t)which * 256 + i) * 3 + p] = o;
    }
}

// ---------------------------------------------------------------------------
// K1b: Wcat[n][k] bf16, n in [0,512), k in [0,512):
//   k <  256 : P_eff[n][k]      = point_w[n][k] / 16        (multiplies u)
//   k >= 256 : PL[n][k-256]     = sum_c pw[n][c]*lr[c][k-256] / 256  (mult x)
// ---------------------------------------------------------------------------
__global__ __launch_bounds__(256) void fold_kernel(
    const float* __restrict__ point_w, const float* __restrict__ lr_w,
    u16* __restrict__ wcat)
{
    const int n = blockIdx.x;
    const int j = threadIdx.x;
    __shared__ float pw[256];
    pw[j] = point_w[(size_t)n * 256 + j];
    __syncthreads();
    float a0 = 0.f, a1 = 0.f, a2 = 0.f, a3 = 0.f;
    for (int c = 0; c < 256; c += 4) {
        a0 += pw[c + 0] * lr_w[(size_t)(c + 0) * 256 + j];
        a1 += pw[c + 1] * lr_w[(size_t)(c + 1) * 256 + j];
        a2 += pw[c + 2] * lr_w[(size_t)(c + 2) * 256 + j];
        a3 += pw[c + 3] * lr_w[(size_t)(c + 3) * 256 + j];
    }
    float acc = (a0 + a1) + (a2 + a3);
    wcat[(size_t)n * 512 + j]       = f2bf(pw[j] * 0.0625f);
    wcat[(size_t)n * 512 + 256 + j] = f2bf(acc * (1.0f / 256.0f));
}

// ---------------------------------------------------------------------------
// K2: fromrgb. x[pos][c] = clamp(sum_k sin(img)*w/sqrt(3) + b, +-256)
// xu layout: [pos][512] bf16, x lives at channels 256..511.
// thread: pos = bid*8 + (t>>5), c0 = (t&31)*8   (coalesced 512B per 32 lanes)
// ---------------------------------------------------------------------------
__global__ __launch_bounds__(256) void fromrgb_kernel(
    const float* __restrict__ img, const float* __restrict__ frw,
    const float* __restrict__ frb, u16* __restrict__ xu)
{
    const int t = threadIdx.x;
    const int pos = blockIdx.x * 8 + (t >> 5);
    const int c0 = (t & 31) * 8;
    const int b = pos >> 14;
    const int hw = pos & 16383;

    const float* ib = img + (size_t)b * 3 * 16384 + hw;
    float s0 = sinf(ib[0]);
    float s1 = sinf(ib[16384]);
    float s2 = sinf(ib[32768]);
    const float g = 0.5773502691896258f;  // 1/sqrt(3)

    union { float4 v[6]; float f[24]; } wv;
    const float4* wp = (const float4*)(frw + (size_t)c0 * 3);
    #pragma unroll
    for (int q = 0; q < 6; q++) wv.v[q] = wp[q];

    union { u16 q[8]; s16x8 v; } ov;
    #pragma unroll
    for (int q = 0; q < 8; q++) {
        float v = (s0 * wv.f[q * 3 + 0] + s1 * wv.f[q * 3 + 1] + s2 * wv.f[q * 3 + 2]) * g
                + frb[c0 + q];
        v = fminf(256.f, fmaxf(-256.f, v));
        ov.q[q] = f2bf(v);
    }
    *(s16x8*)(xu + (size_t)pos * 512 + 256 + c0) = ov.v;
}

// ---------------------------------------------------------------------------
// K3: depthwise 3x3 (vt outer hz), gain 1/3. Reads x (ch 256..511 of xu),
// writes u into ch 0..255 of xu. One thread = one pos x 8 channels.
// ---------------------------------------------------------------------------
__global__ __launch_bounds__(256) void dw_kernel(
    u16* __restrict__ xu, const float* __restrict__ hzvt)
{
    const int t = blockIdx.x * 256 + threadIdx.x;
    const int c0 = (t & 31) * 8;
    const int pos = t >> 5;
    const int w = pos & 127;
    const int h = (pos >> 7) & 127;
    const int b = pos >> 14;

    union { float4 v[6]; float f[24]; } hzw, vtw;
    const float4* hp = (const float4*)(hzvt + (size_t)c0 * 3);
    const float4* vp = (const float4*)(hzvt + 768 + (size_t)c0 * 3);
    #pragma unroll
    for (int q = 0; q < 6; q++) { hzw.v[q] = hp[q]; vtw.v[q] = vp[q]; }

    float acc8[8];
    #pragma unroll
    for (int q = 0; q < 8; q++) acc8[q] = 0.f;

    #pragma unroll
    for (int i = 0; i < 3; i++) {
        int hh = h + i - 1;
        if (hh < 0 || hh > 127) continue;
        float hr[8];
        #pragma unroll
        for (int q = 0; q < 8; q++) hr[q] = 0.f;
        #pragma unroll
        for (int j = 0; j < 3; j++) {
            int ww = w + j - 1;
            if (ww < 0 || ww > 127) continue;
            const u16* xp = xu + ((size_t)((b * 128 + hh) * 128 + ww) * 512 + 256 + c0);
            s16x8 xv = *(const s16x8*)xp;
            #pragma unroll
            for (int q = 0; q < 8; q++) hr[q] += hzw.f[q * 3 + j] * bf2f((u16)xv[q]);
        }
        #pragma unroll
        for (int q = 0; q < 8; q++) acc8[q] += vtw.f[q * 3 + i] * hr[q];
    }

    union { u16 q[8]; s16x8 v; } ov;
    #pragma unroll
    for (int q = 0; q < 8; q++) ov.q[q] = f2bf(acc8[q] * (1.0f / 3.0f));
    *(s16x8*)(xu + (size_t)pos * 512 + c0) = ov.v;
}

// ---------------------------------------------------------------------------
// K4: GEMM  ypre[m][n] = lrelu(sum_k A[m][k]*Wcat[n][k] + bias)  (m97 style)
// A = xu (NHWC, K=512), B^T = wcat.  128x128 tile, BK=32, 4 waves.
// Writes ypre in NCHW-half layout [B][256][128][128] bf16 for the FIR pass.
// ---------------------------------------------------------------------------
__global__ __launch_bounds__(256) void gemm_kernel(
    const u16* __restrict__ xu, const u16* __restrict__ wcat,
    const float* __restrict__ point_b, u16* __restrict__ ypre, int nofs)
{
    __shared__ u16 As[128 * 32];  // [pos][k] rows of 32 bf16 (64B)
    __shared__ u16 Bs[128 * 32];  // [n][k]

    const int tid = threadIdx.x;
    const int bid = blockIdx.x;
    // XCD swizzle: the 2 n-tiles sharing an A-tile land 8 apart (same XCD)
    const int ntile = (bid >> 3) & 1;
    const int mtile = (bid & 7) | ((bid >> 4) << 3);

    const int erow = tid >> 2;   // 0..63
    const int ek = tid & 3;
    const size_t apos0 = (size_t)(mtile * 128 + erow) * 512 + ek * 8;
    const size_t apos1 = apos0 + (size_t)64 * 512;
    const int nbase = nofs + ntile * 128;
    const size_t bpos0 = (size_t)(nbase + erow) * 512 + ek * 8;
    const size_t bpos1 = bpos0 + (size_t)64 * 512;
    u16* as0 = &As[(size_t)tid * 8];
    u16* as1 = &As[(size_t)(tid + 256) * 8];
    u16* bs0 = &Bs[(size_t)tid * 8];
    u16* bs1 = &Bs[(size_t)(tid + 256) * 8];

    const int lane = tid & 63;
    const int wave = tid >> 6;
    const int wm = (wave >> 1) * 64;
    const int wn = (wave & 1) * 64;
    const int l16 = lane & 15;
    const int lq = lane >> 4;

    f32x4 acc[4][4];
    #pragma unroll
    for (int a = 0; a < 4; a++)
        #pragma unroll
        for (int c = 0; c < 4; c++) acc[a][c] = (f32x4){0.f, 0.f, 0.f, 0.f};

    for (int kt = 0; kt < 16; kt++) {
        __syncthreads();
        const int ko = kt * 32;
        ASYNC_COPY16(xu + apos0 + ko, as0);
        ASYNC_COPY16(xu + apos1 + ko, as1);
        ASYNC_COPY16(wcat + bpos0 + ko, bs0);
        ASYNC_COPY16(wcat + bpos1 + ko, bs1);
        __syncthreads();

        s16x8 af[4], bf[4];
        #pragma unroll
        for (int mi = 0; mi < 4; mi++)
            af[mi] = *(const s16x8*)&As[(wm + mi * 16 + l16) * 32 + lq * 8];
        #pragma unroll
        for (int ni = 0; ni < 4; ni++)
            bf[ni] = *(const s16x8*)&Bs[(wn + ni * 16 + l16) * 32 + lq * 8];
        #pragma unroll
        for (int mi = 0; mi < 4; mi++)
            #pragma unroll
            for (int ni = 0; ni < 4; ni++)
                acc[mi][ni] = __builtin_amdgcn_mfma_f32_16x16x32_bf16(
                    af[mi], bf[ni], acc[mi][ni], 0, 0, 0);
    }

    // epilogue: bias + lrelu*sqrt(2) + clamp, store NCHW bf16 (4 w per store)
    const int b = mtile >> 7;
    const int h = mtile & 127;
    #pragma unroll
    for (int ni = 0; ni < 4; ni++) {
        const int nl = ntile * 128 + wn + ni * 16 + l16;  // local n in [0,256)
        const float bias = point_b[nofs + nl];
        u16* drow = ypre + ((size_t)(b * 256 + nl) * 128 + h) * 128;
        #pragma unroll
        for (int mi = 0; mi < 4; mi++) {
            const int w0 = wm + mi * 16 + lq * 4;
            union { u16 q[4]; uint2 d; } pk;
            #pragma unroll
            for (int r = 0; r < 4; r++) {
                float v = acc[mi][ni][r] + bias;
                v = (v >= 0.f) ? v : 0.2f * v;
                v *= 1.4142135623730951f;
                v = fminf(256.f, fmaxf(-256.f, v));
                pk.q[r] = f2bf(v);
            }
            *(uint2*)(drow + w0) = pk.d;
        }
    }
}

// ---------------------------------------------------------------------------
// K5: FIR downsample 2x with separable [1,3,3,1]/8, pad 1.
// One wave per (b, n-local); lane = ow; ring over oh (2 new rows per oh).
// ---------------------------------------------------------------------------
__global__ __launch_bounds__(64) void fir_kernel(
    const u16* __restrict__ ypre, const float* __restrict__ fir,
    float* __restrict__ out, int nofs)
{
    const int bid = blockIdx.x;
    const int lane = threadIdx.x;  // ow 0..63
    const int nl = bid & 255;
    const int b = bid >> 8;
    const u16* src = ypre + (size_t)(b * 256 + nl) * 16384;
    float* dst = out + (size_t)(b * 512 + nofs + nl) * 4096;

    const float f0 = fir[0], f1 = fir[1], f2 = fir[2], f3 = fir[3];

    auto hrow = [&](int r) -> float {
        if (r < 0 || r > 127) return 0.f;
        unsigned raw = *(const unsigned*)(src + (size_t)r * 128 + lane * 2);
        float y0 = bf2f((u16)(raw & 0xffffu));
        float y1 = bf2f((u16)(raw >> 16));
        float ym = __shfl_up(y1, 1u);   // lane l-1's y1 = value at w=2l-1
        if (lane == 0) ym = 0.f;        // w = -1 pad
        float yp = __shfl_down(y0, 1u); // lane l+1's y0 = value at w=2l+2
        if (lane == 63) yp = 0.f;       // w = 128 pad
        return f0 * ym + f1 * y0 + f2 * y1 + f3 * yp;
    };

    float A = 0.f;        // h[2*oh-1], oh=0 -> row -1 = 0
    float Bv = hrow(0);   // h[2*oh]
    for (int oh = 0; oh < 64; oh++) {
        float C = hrow(2 * oh + 1);
        float D = hrow(2 * oh + 2);
        dst[oh * 64 + lane] = f0 * A + f1 * Bv + f2 * C + f3 * D;
        A = C;
        Bv = D;
    }
}

// ---------------------------------------------------------------------------
extern "C" void kernel_launch(void* const* d_in, const int* in_sizes, int n_in,
                              void* d_out, int out_size, void* d_ws, size_t ws_size,
                              hipStream_t stream)
{
    (void)in_sizes; (void)n_in; (void)out_size; (void)ws_size;
    const float* img        = (const float*)d_in[0];
    const float* fromrgb_w  = (const float*)d_in[1];
    const float* fromrgb_b  = (const float*)d_in[2];
    const float* freqs      = (const float*)d_in[3];
    const float* phases     = (const float*)d_in[4];
    const float* hz_outdim  = (const float*)d_in[5];
    const float* vt_outdim  = (const float*)d_in[6];
    const float* gsig       = (const float*)d_in[7];
    const float* lr_w       = (const float*)d_in[8];
    const float* point_w    = (const float*)d_in[9];
    const float* point_b    = (const float*)d_in[10];
    const float* low_filter = (const float*)d_in[11];
    const float* gauss_x    = (const float*)d_in[12];
    const float* fir        = (const float*)d_in[13];

    char* ws = (char*)d_ws;
    u16*   xu   = (u16*)(ws);                      // 262144*512*2  = 256 MiB
    u16*   ypre = (u16*)(ws + 268435456LL);        // 16*256*128*128*2 = 128 MiB
    u16*   wcat = (u16*)(ws + 402653184LL);        // 512*512*2 = 512 KiB
    float* hzvt = (float*)(ws + 403177472LL);      // 2*256*3*4 = 6 KiB
    float* out  = (float*)d_out;

    hipLaunchKernelGGL(gen_kernel, dim3(2), dim3(256), 0, stream,
                       freqs, phases, hz_outdim, vt_outdim, gsig, low_filter, gauss_x, hzvt);
    hipLaunchKernelGGL(fold_kernel, dim3(512), dim3(256), 0, stream,
                       point_w, lr_w, wcat);
    hipLaunchKernelGGL(fromrgb_kernel, dim3(32768), dim3(256), 0, stream,
                       img, fromrgb_w, fromrgb_b, xu);
    hipLaunchKernelGGL(dw_kernel, dim3(32768), dim3(256), 0, stream,
                       xu, hzvt);
    for (int half = 0; half < 2; half++) {
        hipLaunchKernelGGL(gemm_kernel, dim3(4096), dim3(256), 0, stream,
                           xu, wcat, point_b, ypre, half * 256);
        hipLaunchKernelGGL(fir_kernel, dim3(4096), dim3(64), 0, stream,
                           ypre, fir, out, half * 256);
    }
}